// Round 15
// baseline (271.449 us; speedup 1.0000x reference)
//
#include <hip/hip_runtime.h>

#define FI 256
#define FH 64
#define FO 128
#define ASORT_CHUNK 2048
// ushort-view row stride 256: bf16 h1 at ushort[128..191] (mm1 out, read by gather_relu).
// hrelu lives in its own ws buffer (N x 64 bf16) so fused mm2 can write out in place.

typedef __attribute__((ext_vector_type(8))) short bf16x8;
typedef __attribute__((ext_vector_type(4))) float f32x4;

__device__ __forceinline__ ushort f2bf(float x) {   // fp32 -> bf16 RNE
    unsigned b = __float_as_uint(x);
    b += 0x7fffu + ((b >> 16) & 1u);
    return (ushort)(b >> 16);
}
__device__ __forceinline__ float bf2f(ushort u) {
    return __uint_as_float(((unsigned)u) << 16);
}

// ---------------- small kernels ----------------

__global__ void zero_i32(int* __restrict__ p, int n) {
    int i = blockIdx.x * 256 + threadIdx.x;
    if (i < n) p[i] = 0;
}

__global__ void deg_cnt_kernel(const int* __restrict__ dst, int* __restrict__ cnt, int E) {
    int base = blockIdx.x * 1024 + threadIdx.x;
    #pragma unroll
    for (int q = 0; q < 4; ++q) {
        int e = base + q * 256;
        if (e < E) atomicAdd(&cnt[dst[e]], 1);
    }
}

__global__ void dinv_kernel(const int* __restrict__ cnt, float* __restrict__ dinv, int N) {
    int i = blockIdx.x * 256 + threadIdx.x;
    if (i < N) dinv[i] = rsqrtf((float)cnt[i] + 1.0f);
}

// ---------------- CSR build + weight prep ----------------

// hist (blocks < nblkA) + W1 frag prep (16 blocks) + W2 frag prep (8 blocks).
// W1 frag entry e=(c*8+t)*64+l: col=c*16+(l&15), k=t*32+(l>>4)*8+j (validated r8/r9).
// W2 frag entry e=(cblk*2+t2)*64+l: col=cblk*16+(l&15), k=t2*32+(l>>4)*8+j.
__global__ __launch_bounds__(256) void hist_wprep_kernel(const int* __restrict__ dst,
                                                         int* __restrict__ bucket_cnt,
                                                         const float* __restrict__ W1,
                                                         short* __restrict__ WH,
                                                         short* __restrict__ WL,
                                                         const float* __restrict__ W2,
                                                         short* __restrict__ W2H,
                                                         short* __restrict__ W2L,
                                                         int E, int nblkA) {
    if ((int)blockIdx.x >= nblkA) {
        int bid2 = (int)blockIdx.x - nblkA;
        if (bid2 < 16) {
            int f = bid2 * 256 + threadIdx.x;     // float4 idx in 256x64 W1
            float4 wv = *(const float4*)&W1[(size_t)f * 4];
            int k  = f >> 4;
            int c4 = f & 15;
            int j  = k & 7;
            int e0 = ((c4 >> 2) * 8 + (k >> 5)) * 64 + ((k >> 3) & 3) * 16 + (c4 & 3) * 4;
            float vv[4] = {wv.x, wv.y, wv.z, wv.w};
            #pragma unroll
            for (int cc = 0; cc < 4; ++cc) {
                ushort h = f2bf(vv[cc]);
                WH[(e0 + cc) * 8 + j] = (short)h;
                WL[(e0 + cc) * 8 + j] = (short)f2bf(vv[cc] - bf2f(h));
            }
        } else {
            int f = (bid2 - 16) * 256 + threadIdx.x;   // float4 idx in 64x128 W2
            float4 wv = *(const float4*)&W2[(size_t)f * 4];
            int k  = f >> 5;                       // row 0..63
            int c4 = f & 31;
            int j  = k & 7;
            int lk = ((k >> 3) & 3) * 16;
            int t2 = k >> 5;
            float vv[4] = {wv.x, wv.y, wv.z, wv.w};
            #pragma unroll
            for (int cc = 0; cc < 4; ++cc) {
                int col = c4 * 4 + cc;
                int e = ((col >> 4) * 2 + t2) * 64 + lk + (col & 15);
                ushort h = f2bf(vv[cc]);
                W2H[e * 8 + j] = (short)h;
                W2L[e * 8 + j] = (short)f2bf(vv[cc] - bf2f(h));
            }
        }
        return;
    }
    __shared__ int lcnt[256];
    int t = threadIdx.x;
    int base = blockIdx.x * ASORT_CHUNK;
    lcnt[t] = 0;
    __syncthreads();
    #pragma unroll
    for (int j = 0; j < 8; ++j) {
        int e = base + j * 256 + t;
        if (e < E) atomicAdd(&lcnt[((unsigned)dst[e]) >> 8], 1);
    }
    __syncthreads();
    int v = lcnt[t];
    if (v > 0) atomicAdd(&bucket_cnt[t], v);
}

__global__ __launch_bounds__(256) void bucket_scan_kernel(const int* __restrict__ bucket_cnt,
                                                          int* __restrict__ bucket_base,
                                                          int* __restrict__ bucket_pos, int E) {
    __shared__ int sc[256];
    int t = threadIdx.x;
    int sum = bucket_cnt[t];
    sc[t] = sum;
    __syncthreads();
    for (int off = 1; off < 256; off <<= 1) {
        int u = (t >= off) ? sc[t - off] : 0;
        __syncthreads();
        sc[t] += u;
        __syncthreads();
    }
    int excl = sc[t] - sum;
    bucket_base[t] = excl;
    bucket_pos[t]  = excl;
    if (t == 255) bucket_base[256] = sc[255];   // == E
}

// Merged dispatch: blocks [0,nblkA) = Pass A; blocks [nblkA,..) = mm1 v9
// (MFMA; x coalesced through wave-private swizzled LDS; r14-validated, 49us).
__global__ __launch_bounds__(256) void binA_mm1_kernel(const int* __restrict__ src,
                                                       const int* __restrict__ dst,
                                                       int* __restrict__ bucket_pos,
                                                       unsigned* __restrict__ binned, int E,
                                                       const float* __restrict__ x,
                                                       const short* __restrict__ WH,
                                                       const short* __restrict__ WL,
                                                       float* __restrict__ out, int N,
                                                       int nblkA) {
    __shared__ __align__(16) char smem[32768];
    if ((int)blockIdx.x >= nblkA) {
        int bid = (int)blockIdx.x - nblkA;
        int tid = threadIdx.x;
        int wid = tid >> 6;
        int l   = tid & 63;
        int R0  = bid * 64 + wid * 16;          // wave's 16-row strip
        char* LH = smem + wid * 8192;           // [16][128] bf16 hi, row stride 256B, swizzled
        char* LL = LH + 4096;                   // lo plane
        const float4 z4 = make_float4(0.f, 0.f, 0.f, 0.f);

        f32x4 acc[4];
        #pragma unroll
        for (int c = 0; c < 4; ++c) acc[c] = (f32x4){0.f, 0.f, 0.f, 0.f};

        #pragma unroll
        for (int half = 0; half < 2; ++half) {
            #pragma unroll
            for (int it = 0; it < 8; ++it) {
                int f   = it * 64 + l;
                int row = f >> 5;
                int c4  = f & 31;
                int grow = R0 + row;
                float4 v = (grow < N) ? *(const float4*)&x[(size_t)grow * FI + half * 128 + c4 * 4]
                                      : z4;
                ushort h0 = f2bf(v.x), h1 = f2bf(v.y), h2 = f2bf(v.z), h3 = f2bf(v.w);
                uint2 hw, lw;
                hw.x = (unsigned)h0 | ((unsigned)h1 << 16);
                hw.y = (unsigned)h2 | ((unsigned)h3 << 16);
                lw.x = (unsigned)f2bf(v.x - bf2f(h0)) | ((unsigned)f2bf(v.y - bf2f(h1)) << 16);
                lw.y = (unsigned)f2bf(v.z - bf2f(h2)) | ((unsigned)f2bf(v.w - bf2f(h3)) << 16);
                int byt = (row * 256 + c4 * 8) ^ ((row & 7) << 4);
                *(uint2*)(LH + byt) = hw;
                *(uint2*)(LL + byt) = lw;
            }
            #pragma unroll
            for (int tl = 0; tl < 4; ++tl) {
                int t = half * 4 + tl;
                int r = l & 15, kg = l >> 4;
                int byt = (r * 256 + tl * 64 + kg * 16) ^ ((r & 7) << 4);
                bf16x8 ah = *(const bf16x8*)(LH + byt);
                bf16x8 al = *(const bf16x8*)(LL + byt);
                #pragma unroll
                for (int c = 0; c < 4; ++c) {
                    int e = (c * 8 + t) * 64 + l;
                    bf16x8 bh = *(const bf16x8*)&WH[(size_t)e * 8];
                    bf16x8 bl = *(const bf16x8*)&WL[(size_t)e * 8];
                    acc[c] = __builtin_amdgcn_mfma_f32_16x16x32_bf16(ah, bh, acc[c], 0, 0, 0);
                    acc[c] = __builtin_amdgcn_mfma_f32_16x16x32_bf16(ah, bl, acc[c], 0, 0, 0);
                    acc[c] = __builtin_amdgcn_mfma_f32_16x16x32_bf16(al, bh, acc[c], 0, 0, 0);
                }
            }
        }
        {
            int rbase = R0 + (l >> 4) * 4;
            #pragma unroll
            for (int r = 0; r < 4; ++r) {
                int row = rbase + r;
                if (row < N) {
                    ushort* ob = (ushort*)out + (size_t)row * 256 + 128;
                    #pragma unroll
                    for (int c = 0; c < 4; ++c)
                        ob[c * 16 + (l & 15)] = f2bf(acc[c][r]);
                }
            }
        }
        return;
    }
    // ---- binA path (unchanged; smem union layout) ----
    int* lcnt   = (int*)smem;
    int* lbase  = (int*)smem + 256;
    int* gbase  = (int*)smem + 512;
    int* sc     = (int*)smem + 768;
    unsigned* sorted = (unsigned*)(smem + 4096);
    int t = threadIdx.x;
    int base = blockIdx.x * ASORT_CHUNK;
    lcnt[t] = 0;
    __syncthreads();
    unsigned pk[8];
    short bb[8];
    short mi[8];
    #pragma unroll
    for (int j = 0; j < 8; ++j) {
        int e = base + j * 256 + t;
        if (e < E) {
            unsigned s = (unsigned)src[e];
            unsigned d = (unsigned)dst[e];
            pk[j] = s | (d << 16);
            int b = (int)(d >> 8);
            bb[j] = (short)b;
            mi[j] = (short)atomicAdd(&lcnt[b], 1);
        } else {
            bb[j] = -1;
        }
    }
    __syncthreads();
    int v = lcnt[t];
    sc[t] = v;
    __syncthreads();
    #pragma unroll
    for (int off = 1; off < 256; off <<= 1) {
        int u = (t >= off) ? sc[t - off] : 0;
        __syncthreads();
        sc[t] += u;
        __syncthreads();
    }
    lbase[t] = sc[t] - v;
    if (v > 0) gbase[t] = atomicAdd(&bucket_pos[t], v);
    __syncthreads();
    #pragma unroll
    for (int j = 0; j < 8; ++j)
        if (bb[j] >= 0) sorted[lbase[(int)bb[j]] + (int)mi[j]] = pk[j];
    int tot = sc[255];
    __syncthreads();
    for (int i = t; i < tot; i += 256) {
        unsigned vv = sorted[i];
        int b = (int)(vv >> 24);
        binned[gbase[b] + (i - lbase[b])] = vv;
    }
}

// Pass B: one block per bucket; per-node histogram+scan in LDS, writes row_start/cnt/dinv,
// then scatters rec4 (src-only) inside the bucket's ~32KB region.
__global__ __launch_bounds__(256) void binB_kernel(const int* __restrict__ bucket_base,
                                                   const unsigned* __restrict__ binned,
                                                   int* __restrict__ rec4,
                                                   int* __restrict__ row_start,
                                                   int* __restrict__ cnt,
                                                   float* __restrict__ dinv, int N) {
    __shared__ int lcnt[256];
    __shared__ int sc[256];
    __shared__ int lstart[256];
    __shared__ int loff[256];
    int t = threadIdx.x;
    int d0 = blockIdx.x << 8;
    int start = bucket_base[blockIdx.x];
    int end   = bucket_base[blockIdx.x + 1];
    lcnt[t] = 0;
    __syncthreads();
    for (int i = start + t; i < end; i += 256)
        atomicAdd(&lcnt[(binned[i] >> 16) & 0xffu], 1);
    __syncthreads();
    int v = lcnt[t];
    sc[t] = v;
    __syncthreads();
    for (int off = 1; off < 256; off <<= 1) {
        int u = (t >= off) ? sc[t - off] : 0;
        __syncthreads();
        sc[t] += u;
        __syncthreads();
    }
    int st = start + sc[t] - v;
    lstart[t] = st;
    loff[t] = 0;
    if (d0 + t < N) {
        row_start[d0 + t] = st;
        cnt[d0 + t] = v;
        dinv[d0 + t] = rsqrtf((float)v + 1.0f);
    }
    __syncthreads();
    int i = start + t;
    for (; i + 768 < end; i += 1024) {
        unsigned v0 = binned[i];
        unsigned v1 = binned[i + 256];
        unsigned v2 = binned[i + 512];
        unsigned v3 = binned[i + 768];
        int dA = (int)((v0 >> 16) & 0xffu); int kA = atomicAdd(&loff[dA], 1);
        rec4[lstart[dA] + kA] = (int)(v0 & 0xffffu);
        int dB = (int)((v1 >> 16) & 0xffu); int kB = atomicAdd(&loff[dB], 1);
        rec4[lstart[dB] + kB] = (int)(v1 & 0xffffu);
        int dC = (int)((v2 >> 16) & 0xffu); int kC = atomicAdd(&loff[dC], 1);
        rec4[lstart[dC] + kC] = (int)(v2 & 0xffffu);
        int dD = (int)((v3 >> 16) & 0xffu); int kD = atomicAdd(&loff[dD], 1);
        rec4[lstart[dD] + kD] = (int)(v3 & 0xffffu);
    }
    for (; i < end; i += 256) {
        unsigned v4 = binned[i];
        int d = (int)((v4 >> 16) & 0xffu);
        int k = atomicAdd(&loff[d], 1);
        rec4[lstart[d] + k] = (int)(v4 & 0xffffu);
    }
}

// ---------------- gather-side aggregation ----------------

#define ACC8(hv, wt)                                                   \
    acc[0] = fmaf(__uint_as_float((hv).x << 16),         wt, acc[0]);  \
    acc[1] = fmaf(__uint_as_float((hv).x & 0xffff0000u), wt, acc[1]);  \
    acc[2] = fmaf(__uint_as_float((hv).y << 16),         wt, acc[2]);  \
    acc[3] = fmaf(__uint_as_float((hv).y & 0xffff0000u), wt, acc[3]);  \
    acc[4] = fmaf(__uint_as_float((hv).z << 16),         wt, acc[4]);  \
    acc[5] = fmaf(__uint_as_float((hv).z & 0xffff0000u), wt, acc[5]);  \
    acc[6] = fmaf(__uint_as_float((hv).w << 16),         wt, acc[6]);  \
    acc[7] = fmaf(__uint_as_float((hv).w & 0xffff0000u), wt, acc[7]);

// layer 1: gather bf16 h1 (out ushort cols [128..191]); hrelu -> hrelu_ws (N x 64 bf16).
__global__ void gather_relu_kernel(const int* __restrict__ rec4, const int* __restrict__ row_start,
                                   const int* __restrict__ cnt, const float* __restrict__ dinv,
                                   const float* __restrict__ b1, const float* __restrict__ out,
                                   ushort* __restrict__ hrelu, int N) {
    int node = blockIdx.x * 4 + (threadIdx.x >> 6);
    if (node >= N) return;
    int L = threadIdx.x & 63;
    int g = L >> 3;
    int q = L & 7;
    const ushort* hb = (const ushort*)out;
    int beg = row_start[node];
    int n   = cnt[node];
    float dvd = dinv[node];
    float acc[8] = {0.f, 0.f, 0.f, 0.f, 0.f, 0.f, 0.f, 0.f};
    for (int c0 = 0; c0 < n; c0 += 64) {
        int idx_l = c0 + L;
        int sreg = node;
        float wreg = 0.f;
        if (idx_l < n) {
            sreg = rec4[beg + idx_l];
            wreg = dinv[sreg] * dvd;
        }
        int m = n - c0; if (m > 64) m = 64;
        int umax = (m + 7) >> 3;
        uint4 hv[8];
        #pragma unroll
        for (int u = 0; u < 8; ++u) {
            if (u < umax) {
                int sidx = __shfl(sreg, u * 8 + g, 64);
                hv[u] = *(const uint4*)(hb + (size_t)sidx * 256 + 128 + q * 8);
            }
        }
        #pragma unroll
        for (int u = 0; u < 8; ++u) {
            if (u < umax) {
                float wt = __shfl(wreg, u * 8 + g, 64);
                ACC8(hv[u], wt)
            }
        }
    }
    #pragma unroll
    for (int off = 8; off < 64; off <<= 1)
        #pragma unroll
        for (int j = 0; j < 8; ++j)
            acc[j] += __shfl_xor(acc[j], off, 64);
    if (L < 8) {
        float dv2 = dvd * dvd;
        uint4 ho = *(const uint4*)(hb + (size_t)node * 256 + 128 + q * 8);
        float4 bl = *(const float4*)&b1[q * 8];
        float4 bh = *(const float4*)&b1[q * 8 + 4];
        float r0 = fmaxf(acc[0] + dv2 * __uint_as_float(ho.x << 16)         + bl.x, 0.f);
        float r1 = fmaxf(acc[1] + dv2 * __uint_as_float(ho.x & 0xffff0000u) + bl.y, 0.f);
        float r2 = fmaxf(acc[2] + dv2 * __uint_as_float(ho.y << 16)         + bl.z, 0.f);
        float r3 = fmaxf(acc[3] + dv2 * __uint_as_float(ho.y & 0xffff0000u) + bl.w, 0.f);
        float r4 = fmaxf(acc[4] + dv2 * __uint_as_float(ho.z << 16)         + bh.x, 0.f);
        float r5 = fmaxf(acc[5] + dv2 * __uint_as_float(ho.z & 0xffff0000u) + bh.y, 0.f);
        float r6 = fmaxf(acc[6] + dv2 * __uint_as_float(ho.w << 16)         + bh.z, 0.f);
        float r7 = fmaxf(acc[7] + dv2 * __uint_as_float(ho.w & 0xffff0000u) + bh.w, 0.f);
        uint4 st;
        st.x = (unsigned)f2bf(r0) | ((unsigned)f2bf(r1) << 16);
        st.y = (unsigned)f2bf(r2) | ((unsigned)f2bf(r3) << 16);
        st.z = (unsigned)f2bf(r4) | ((unsigned)f2bf(r5) << 16);
        st.w = (unsigned)f2bf(r6) | ((unsigned)f2bf(r7) << 16);
        *(uint4*)(hrelu + (size_t)node * 64 + q * 8) = st;
    }
}

// Fused layer-2 gather + mm2. Block = 16 nodes, 4 waves (4 nodes/wave sequential).
// Phase 1: gather combined = agg + dv^2*own from hrelu_ws, pack bf16 hi/lo into 4KB
// swizzled LDS. Phase 2: MFMA mm2 (A from LDS, B = global W2 frags), +b2, write final out.
// Race-free: reads hrelu_ws (never written here), writes out rows of its own nodes only.
__global__ __launch_bounds__(256) void gcomb_mm2_kernel(const int* __restrict__ rec4,
                                                        const int* __restrict__ row_start,
                                                        const int* __restrict__ cnt,
                                                        const float* __restrict__ dinv,
                                                        const ushort* __restrict__ hrelu,
                                                        const short* __restrict__ W2H,
                                                        const short* __restrict__ W2L,
                                                        const float* __restrict__ b2,
                                                        float* __restrict__ out, int N) {
    __shared__ __align__(16) char csm[4096];   // [16][64] bf16 hi + lo, swizzled
    char* CH = csm;
    char* CL = csm + 2048;
    int tid = threadIdx.x;
    int wid = tid >> 6;
    int L   = tid & 63;
    int g   = L >> 3;
    int q   = L & 7;
    int R0  = blockIdx.x * 16;

    #pragma unroll
    for (int i = 0; i < 4; ++i) {
        int node = R0 + wid * 4 + i;
        float acc[8] = {0.f, 0.f, 0.f, 0.f, 0.f, 0.f, 0.f, 0.f};
        int beg = 0, n = 0;
        float dvd = 0.f;
        if (node < N) { beg = row_start[node]; n = cnt[node]; dvd = dinv[node]; }
        for (int c0 = 0; c0 < n; c0 += 64) {
            int idx_l = c0 + L;
            int sreg = node;
            float wreg = 0.f;
            if (idx_l < n) {
                sreg = rec4[beg + idx_l];
                wreg = dinv[sreg] * dvd;
            }
            int m = n - c0; if (m > 64) m = 64;
            int umax = (m + 7) >> 3;
            uint4 hv[8];
            #pragma unroll
            for (int u = 0; u < 8; ++u) {
                if (u < umax) {
                    int sidx = __shfl(sreg, u * 8 + g, 64);
                    hv[u] = *(const uint4*)(hrelu + (size_t)sidx * 64 + q * 8);
                }
            }
            #pragma unroll
            for (int u = 0; u < 8; ++u) {
                if (u < umax) {
                    float wt = __shfl(wreg, u * 8 + g, 64);
                    ACC8(hv[u], wt)
                }
            }
        }
        #pragma unroll
        for (int off = 8; off < 64; off <<= 1)
            #pragma unroll
            for (int j = 0; j < 8; ++j)
                acc[j] += __shfl_xor(acc[j], off, 64);
        if (L < 8) {
            if (node < N) {
                float dv2 = dvd * dvd;
                uint4 ho = *(const uint4*)(hrelu + (size_t)node * 64 + q * 8);
                acc[0] += dv2 * __uint_as_float(ho.x << 16);
                acc[1] += dv2 * __uint_as_float(ho.x & 0xffff0000u);
                acc[2] += dv2 * __uint_as_float(ho.y << 16);
                acc[3] += dv2 * __uint_as_float(ho.y & 0xffff0000u);
                acc[4] += dv2 * __uint_as_float(ho.z << 16);
                acc[5] += dv2 * __uint_as_float(ho.z & 0xffff0000u);
                acc[6] += dv2 * __uint_as_float(ho.w << 16);
                acc[7] += dv2 * __uint_as_float(ho.w & 0xffff0000u);
            }
            int row = wid * 4 + i;
            ushort h0 = f2bf(acc[0]), h1 = f2bf(acc[1]), h2 = f2bf(acc[2]), h3 = f2bf(acc[3]);
            ushort h4 = f2bf(acc[4]), h5 = f2bf(acc[5]), h6 = f2bf(acc[6]), h7 = f2bf(acc[7]);
            uint4 hw, lw;
            hw.x = (unsigned)h0 | ((unsigned)h1 << 16);
            hw.y = (unsigned)h2 | ((unsigned)h3 << 16);
            hw.z = (unsigned)h4 | ((unsigned)h5 << 16);
            hw.w = (unsigned)h6 | ((unsigned)h7 << 16);
            lw.x = (unsigned)f2bf(acc[0] - bf2f(h0)) | ((unsigned)f2bf(acc[1] - bf2f(h1)) << 16);
            lw.y = (unsigned)f2bf(acc[2] - bf2f(h2)) | ((unsigned)f2bf(acc[3] - bf2f(h3)) << 16);
            lw.z = (unsigned)f2bf(acc[4] - bf2f(h4)) | ((unsigned)f2bf(acc[5] - bf2f(h5)) << 16);
            lw.w = (unsigned)f2bf(acc[6] - bf2f(h6)) | ((unsigned)f2bf(acc[7] - bf2f(h7)) << 16);
            int byt = (row * 128 + L * 16) ^ ((row & 7) << 4);
            *(uint4*)(CH + byt) = hw;
            *(uint4*)(CL + byt) = lw;
        }
    }
    __syncthreads();

    // mm2: wave wid computes cols [wid*32, wid*32+32)
    f32x4 acc2[2];
    acc2[0] = (f32x4){0.f, 0.f, 0.f, 0.f};
    acc2[1] = (f32x4){0.f, 0.f, 0.f, 0.f};
    {
        int r = L & 15, kg = L >> 4;
        #pragma unroll
        for (int t = 0; t < 2; ++t) {
            int byt = (r * 128 + t * 64 + kg * 16) ^ ((r & 7) << 4);
            bf16x8 ah = *(const bf16x8*)(CH + byt);
            bf16x8 al = *(const bf16x8*)(CL + byt);
            #pragma unroll
            for (int c = 0; c < 2; ++c) {
                int e = ((wid * 2 + c) * 2 + t) * 64 + L;
                bf16x8 bh = *(const bf16x8*)&W2H[(size_t)e * 8];
                bf16x8 bl = *(const bf16x8*)&W2L[(size_t)e * 8];
                acc2[c] = __builtin_amdgcn_mfma_f32_16x16x32_bf16(ah, bh, acc2[c], 0, 0, 0);
                acc2[c] = __builtin_amdgcn_mfma_f32_16x16x32_bf16(ah, bl, acc2[c], 0, 0, 0);
                acc2[c] = __builtin_amdgcn_mfma_f32_16x16x32_bf16(al, bh, acc2[c], 0, 0, 0);
            }
        }
    }
    #pragma unroll
    for (int c = 0; c < 2; ++c) {
        int col = wid * 32 + c * 16 + (L & 15);
        float bb = b2[col];
        int rbase = R0 + (L >> 4) * 4;
        #pragma unroll
        for (int rr = 0; rr < 4; ++rr) {
            int row = rbase + rr;
            if (row < N) out[(size_t)row * FO + col] = acc2[c][rr] + bb;
        }
    }
}

// ---------------- fallback kernels (workspace-free path) ----------------

__global__ __launch_bounds__(512) void mm1_mfma(const float* __restrict__ x,
                                                const float* __restrict__ W1,
                                                float* __restrict__ out, int N) {
    __shared__ short bfH[2048 * 8];
    __shared__ short bfL[2048 * 8];
    int tid = threadIdx.x;
    #pragma unroll
    for (int i = 0; i < 8; ++i) {
        int f = i * 512 + tid;
        float4 wv = *(const float4*)&W1[(size_t)f * 4];
        int k  = f >> 4;
        int c4 = f & 15;
        int j  = k & 7;
        int e0 = ((c4 >> 2) * 8 + (k >> 5)) * 64 + ((k >> 3) & 3) * 16 + (c4 & 3) * 4;
        float vv[4] = {wv.x, wv.y, wv.z, wv.w};
        #pragma unroll
        for (int cc = 0; cc < 4; ++cc) {
            ushort h = f2bf(vv[cc]);
            bfH[(e0 + cc) * 8 + j] = (short)h;
            bfL[(e0 + cc) * 8 + j] = (short)f2bf(vv[cc] - bf2f(h));
        }
    }
    __syncthreads();
    int wid = tid >> 6;
    int l   = tid & 63;
    int R0  = blockIdx.x * 128;
    int rowA = R0 + wid * 16 + (l & 15);
    int kg   = l >> 4;
    const float* xr = x + (size_t)rowA * FI;
    bool ok = rowA < N;
    const float4 z4 = make_float4(0.f, 0.f, 0.f, 0.f);
    f32x4 acc[4];
    #pragma unroll
    for (int c = 0; c < 4; ++c) acc[c] = (f32x4){0.f, 0.f, 0.f, 0.f};
    float4 xa = ok ? *(const float4*)&xr[kg * 8]     : z4;
    float4 xb = ok ? *(const float4*)&xr[kg * 8 + 4] : z4;
    #pragma unroll
    for (int t = 0; t < 8; ++t) {
        bf16x8 ah, al;
        {
            float va[8] = {xa.x, xa.y, xa.z, xa.w, xb.x, xb.y, xb.z, xb.w};
            #pragma unroll
            for (int j = 0; j < 8; ++j) {
                ushort h = f2bf(va[j]);
                ah[j] = (short)h;
                al[j] = (short)f2bf(va[j] - bf2f(h));
            }
        }
        if (t < 7) {
            int kb = (t + 1) * 32 + kg * 8;
            xa = ok ? *(const float4*)&xr[kb]     : z4;
            xb = ok ? *(const float4*)&xr[kb + 4] : z4;
        }
        #pragma unroll
        for (int c = 0; c < 4; ++c) {
            int e = (c * 8 + t) * 64 + l;
            bf16x8 bh = *(const bf16x8*)&bfH[e * 8];
            bf16x8 bl = *(const bf16x8*)&bfL[e * 8];
            acc[c] = __builtin_amdgcn_mfma_f32_16x16x32_bf16(ah, bh, acc[c], 0, 0, 0);
            acc[c] = __builtin_amdgcn_mfma_f32_16x16x32_bf16(ah, bl, acc[c], 0, 0, 0);
            acc[c] = __builtin_amdgcn_mfma_f32_16x16x32_bf16(al, bh, acc[c], 0, 0, 0);
        }
    }
    {
        int rbase = R0 + wid * 16 + (l >> 4) * 4;
        #pragma unroll
        for (int r = 0; r < 4; ++r) {
            int row = rbase + r;
            if (row < N) {
                ushort* ob = (ushort*)out + (size_t)row * 256 + 128;
                #pragma unroll
                for (int c = 0; c < 4; ++c)
                    ob[c * 16 + (l & 15)] = f2bf(acc[c][r]);
            }
        }
    }
}

// mm2 (fallback): out_row = combined(float[0..63]) @ W2 + b2, in place.
__global__ __launch_bounds__(256) void mm2_tiled(const float* __restrict__ W2,
                                                 const float* __restrict__ b2,
                                                 float* __restrict__ out, int N) {
    __shared__ float xs[64][68];
    __shared__ float ws[64][128];
    int tid = threadIdx.x;
    int R0  = blockIdx.x * 64;
    int ty  = tid >> 4;
    int tx  = tid & 15;

    {
        int sr = tid >> 2;
        int l4 = tid & 3;
        int grow = R0 + sr;
        bool ok = grow < N;
        const float* orow = out + (size_t)grow * FO;
        #pragma unroll
        for (int q = 0; q < 4; ++q) {
            int j0 = (l4 + 4 * q) * 4;
            float4 a = ok ? *(const float4*)&orow[j0] : make_float4(0.f, 0.f, 0.f, 0.f);
            xs[j0 + 0][sr] = a.x;
            xs[j0 + 1][sr] = a.y;
            xs[j0 + 2][sr] = a.z;
            xs[j0 + 3][sr] = a.w;
        }
    }
    #pragma unroll
    for (int q = 0; q < 8; ++q) {
        int f = tid + q * 256;
        *(float4*)&ws[f >> 5][(f & 31) * 4] = *(const float4*)&W2[(size_t)f * 4];
    }
    __syncthreads();

    float acc[4][8];
    #pragma unroll
    for (int i = 0; i < 4; ++i)
        #pragma unroll
        for (int j = 0; j < 8; ++j) acc[i][j] = 0.f;

    #pragma unroll 4
    for (int k = 0; k < FH; ++k) {
        float4 a  = *(const float4*)&xs[k][ty * 4];
        float4 bl = *(const float4*)&ws[k][tx * 4];
        float4 bh = *(const float4*)&ws[k][64 + tx * 4];
        float av[4] = {a.x, a.y, a.z, a.w};
        float bv[8] = {bl.x, bl.y, bl.z, bl.w, bh.x, bh.y, bh.z, bh.w};
        #pragma unroll
        for (int i = 0; i < 4; ++i)
            #pragma unroll
            for (int j = 0; j < 8; ++j)
                acc[i][j] = fmaf(av[i], bv[j], acc[i][j]);
    }

    float4 b2l = *(const float4*)&b2[tx * 4];
    float4 b2h = *(const float4*)&b2[64 + tx * 4];
    #pragma unroll
    for (int i = 0; i < 4; ++i) {
        int row = R0 + ty * 4 + i;
        if (row < N) {
            float* o = out + (size_t)row * FO;
            *(float4*)&o[tx * 4] = make_float4(acc[i][0] + b2l.x, acc[i][1] + b2l.y,
                                               acc[i][2] + b2l.z, acc[i][3] + b2l.w);
            *(float4*)&o[64 + tx * 4] = make_float4(acc[i][4] + b2h.x, acc[i][5] + b2h.y,
                                                    acc[i][6] + b2h.z, acc[i][7] + b2h.w);
        }
    }
}

// ---------------- fallback (atomic scatter) pieces — all fp32 ----------------

__global__ void expand_hs1_kernel(float* __restrict__ out, int N) {
    int row = blockIdx.x * 4 + (threadIdx.x >> 6);
    if (row >= N) return;
    int lane = threadIdx.x & 63;
    float v = bf2f(((const ushort*)out)[(size_t)row * 256 + 128 + lane]);
    out[(size_t)row * FO + FH + lane] = v;
}

__global__ void zero_half_kernel(float* __restrict__ out, int half, int N) {
    int i = blockIdx.x * 256 + threadIdx.x;
    if (i >= N * FH) return;
    out[(size_t)(i >> 6) * FO + half + (i & 63)] = 0.f;
}

__global__ void scatter_half_kernel(const int* __restrict__ src, const int* __restrict__ dst,
                                    const float* __restrict__ dinv, float* __restrict__ out,
                                    int rh, int wh, int E) {
    int e = blockIdx.x * 4 + (threadIdx.x >> 6);
    if (e >= E) return;
    int lane = threadIdx.x & 63;
    int s = src[e];
    int d = dst[e];
    float w = dinv[s] * dinv[d];
    atomicAdd(&out[(size_t)d * FO + wh + lane], out[(size_t)s * FO + rh + lane] * w);
}

__global__ void finish1_kernel(float* __restrict__ out, const float* __restrict__ dinv,
                               const float* __restrict__ b1, int N) {
    int i = blockIdx.x * 256 + threadIdx.x;
    if (i >= N * FH) return;
    int row = i >> 6;
    int c   = i & 63;
    size_t base = (size_t)row * FO;
    float dv = dinv[row];
    out[base + c] = fmaxf(out[base + c] + dv * dv * out[base + FH + c] + b1[c], 0.f);
}

__global__ void finish2_kernel(float* __restrict__ out, const float* __restrict__ dinv, int N) {
    int i = blockIdx.x * 256 + threadIdx.x;
    if (i >= N * FH) return;
    int row = i >> 6;
    int c   = i & 63;
    size_t base = (size_t)row * FO;
    float dv = dinv[row];
    out[base + c] = out[base + FH + c] + dv * dv * out[base + c];
}

extern "C" void kernel_launch(void* const* d_in, const int* in_sizes, int n_in,
                              void* d_out, int out_size, void* d_ws, size_t ws_size,
                              hipStream_t stream) {
    const float* x  = (const float*)d_in[0];
    const int*   ei = (const int*)d_in[1];
    const float* W1 = (const float*)d_in[2];
    const float* b1 = (const float*)d_in[3];
    const float* W2 = (const float*)d_in[4];
    const float* b2 = (const float*)d_in[5];
    float* out = (float*)d_out;

    int N = in_sizes[0] / FI;     // 50000
    int E = in_sizes[1] / 2;      // 1600000
    const int* src = ei;
    const int* dst = ei + E;

    char* w = (char*)d_ws;
    float* dinv        = (float*)w;      w += (size_t)N * 4;
    int*   cnt         = (int*)w;        w += (size_t)N * 4;
    int*   row_start   = (int*)w;        w += (size_t)N * 4;
    int*   bucket_cnt  = (int*)w;        w += 256 * 4;
    int*   bucket_pos  = (int*)w;        w += 256 * 4;
    int*   bucket_base = (int*)w;        w += 260 * 4;
    short* wfragH      = (short*)w;      w += 2048 * 8 * 2;   // 32KB
    short* wfragL      = (short*)w;      w += 2048 * 8 * 2;   // 32KB
    short* w2fragH     = (short*)w;      w += 1024 * 8 * 2;   // 16KB
    short* w2fragL     = (short*)w;      w += 1024 * 8 * 2;   // 16KB
    ushort* hrelu      = (ushort*)w;     w += (size_t)N * 64 * 2;   // 6.4MB
    unsigned* binned   = (unsigned*)w;   w += (size_t)E * 4;
    int*   rec4        = (int*)w;        w += (size_t)E * 4;
    size_t need = (size_t)(w - (char*)d_ws);   // ~20MB

    int nblkA = (E + ASORT_CHUNK - 1) / ASORT_CHUNK;   // 782
    int nmm1  = (N + 63) / 64;                         // 782
    int nbk   = (N + 255) >> 8;                        // 196 buckets for N=50000

    if (ws_size >= need && N <= 65536) {
        zero_i32<<<1, 256, 0, stream>>>(bucket_cnt, 256);
        hist_wprep_kernel<<<nblkA + 24, 256, 0, stream>>>(dst, bucket_cnt, W1, wfragH, wfragL,
                                                          W2, w2fragH, w2fragL, E, nblkA);
        bucket_scan_kernel<<<1, 256, 0, stream>>>(bucket_cnt, bucket_base, bucket_pos, E);
        binA_mm1_kernel<<<nblkA + nmm1, 256, 0, stream>>>(src, dst, bucket_pos, binned, E,
                                                          x, wfragH, wfragL, out, N, nblkA);
        binB_kernel<<<nbk, 256, 0, stream>>>(bucket_base, binned, rec4, row_start, cnt, dinv, N);

        gather_relu_kernel<<<(N + 3) / 4, 256, 0, stream>>>(rec4, row_start, cnt, dinv, b1,
                                                            out, hrelu, N);
        gcomb_mm2_kernel<<<(N + 15) / 16, 256, 0, stream>>>(rec4, row_start, cnt, dinv, hrelu,
                                                            w2fragH, w2fragL, b2, out, N);
    } else {
        // fallback: atomic scatter path, all fp32 (LDS-staged mm1)
        zero_i32<<<(N + 255) / 256, 256, 0, stream>>>(cnt, N);
        deg_cnt_kernel<<<(E + 1023) / 1024, 256, 0, stream>>>(dst, cnt, E);
        dinv_kernel<<<(N + 255) / 256, 256, 0, stream>>>(cnt, dinv, N);
        mm1_mfma<<<(N + 127) / 128, 512, 0, stream>>>(x, W1, out, N);
        expand_hs1_kernel<<<(N + 3) / 4, 256, 0, stream>>>(out, N);
        zero_half_kernel<<<((N * FH) + 255) / 256, 256, 0, stream>>>(out, 0, N);
        scatter_half_kernel<<<(E + 3) / 4, 256, 0, stream>>>(src, dst, dinv, out, FH, 0, E);
        finish1_kernel<<<((N * FH) + 255) / 256, 256, 0, stream>>>(out, dinv, b1, N);
        zero_half_kernel<<<((N * FH) + 255) / 256, 256, 0, stream>>>(out, FH, N);
        scatter_half_kernel<<<(E + 3) / 4, 256, 0, stream>>>(src, dst, dinv, out, 0, FH, E);
        finish2_kernel<<<((N * FH) + 255) / 256, 256, 0, stream>>>(out, dinv, N);
        mm2_tiled<<<(N + 63) / 64, 256, 0, stream>>>(W2, b2, out, N);
    }
}